// Round 7
// baseline (156.026 us; speedup 1.0000x reference)
//
#include <hip/hip_runtime.h>
#include <math.h>

// MoE top-2-of-8: B=1024, I=512, H=2048, O=512, E=8, K=2.
// R15: canonical double-buffered BOTH-operand LDS GEMM (m97 schedule).
// Diagnosis: R8-R14 all streamed A per-lane from global inside the MFMA loop
// -> per-wave serial load chains (R11: 42.9us = 96 loads x ~1000cyc exactly);
// VGPR caps (48-64) made compiler pipelining impossible. Fix: stage A AND B
// into LDS, double-buffered, one barrier per K-chunk; inner loop is pure
// ds_read_b128 + MFMA.
//  - A: global_load_lds w=16 into fragment-linear 1KB subtiles [16m x 32k]
//    (per-lane pre-permuted global src; LDS dest wave-uniform+lane*16 --
//    R13-verified pattern). fc1 gathers rows via ballot-scan slot list.
//  - B: fp32 W read contiguous (2x float4/thread/chunk), T14 split: loads
//    issued BEFORE compute, cvt+ds_write AFTER compute, before barrier.
//    LDS [n][k] rows, BSTR=72 (144B stride, R7-proven conflict pattern).
//  - Tiles: BM=128 BN=64 BK=64, 512 thr = 8 waves (4wm x 2wn), each wave
//    32m x 32n, acc[2][2], 8 MFMA + 8 ds_read per chunk.
//  - fc1: K=512 (8 chunks), grid 512 = 8e x 32nx x 2my, e=bid&7 (XCD).
//  - fc2: K-half=1024 (16 chunks), kc=2 -> y2 partials, grid 256.
//  - __launch_bounds__(512,4) -> 128 VGPR; LDS ~55KB -> 2 blk/CU.
// NOTE: dur_us includes ~81us of harness 256MB poison fills (2 x 40.5us).

#define B_TOK 1024
#define I_DIM 512
#define H_DIM 2048
#define O_DIM 512
#define E_NUM 8
#define CAP   1024                       // per-expert slot capacity

#define WS_COUNTS   0                    // 8 ints (written by fc1 nx==0,my==0)
#define WS_TOK_E    64                   // [1024][2] int
#define WS_TOK_W    8256                 // [1024][2] float
#define WS_TOK_SLOT 16448                // [1024][2] int
#define WS_XB       65536                // [1024][512] bf16 = 1 MB
#define WS_HB       1114112              // [8*1024][2048] bf16 = 32 MB
#define WS_Y2       34668544             // [2][8192][512] f32 = 32 MB

typedef __attribute__((ext_vector_type(8))) __bf16 bf16x8;
typedef __attribute__((ext_vector_type(4))) __bf16 bf16x4;
typedef __attribute__((ext_vector_type(2))) __bf16 bf16x2;
typedef __attribute__((ext_vector_type(4))) float f32x4;

#define MFMA16 __builtin_amdgcn_mfma_f32_16x16x32_bf16
#define BSTRB 72                         // B LDS row stride (64 + 8)

// async global->LDS, 16B/lane; dest wave-uniform base (+lane*16 by HW),
// src per-lane.
__device__ __forceinline__ void gll16(const __bf16* g, __bf16* l)
{
    __builtin_amdgcn_global_load_lds(
        (const __attribute__((address_space(1))) uint32_t*)g,
        (__attribute__((address_space(3))) uint32_t*)(uintptr_t)(void*)l,
        16, 0, 0);
}

// ---------------------------------------------------------------------------
// Gating: one wave per token. Also converts the token's x row to bf16 (xb).
__global__ __launch_bounds__(256) void gating_kernel(
    const float* __restrict__ x, const float* __restrict__ Wg,
    const float* __restrict__ bg, __bf16* __restrict__ xb,
    int* __restrict__ tok_e, float* __restrict__ tok_w)
{
    const int lane = threadIdx.x & 63;
    const int t = blockIdx.x * 4 + (threadIdx.x >> 6);
    const float4* x4 = (const float4*)(x + (size_t)t * I_DIM);
    float4 va = x4[lane], vb = x4[lane + 64];
    bf16x4 oa, ob;
    oa[0] = (__bf16)va.x; oa[1] = (__bf16)va.y;
    oa[2] = (__bf16)va.z; oa[3] = (__bf16)va.w;
    ob[0] = (__bf16)vb.x; ob[1] = (__bf16)vb.y;
    ob[2] = (__bf16)vb.z; ob[3] = (__bf16)vb.w;
    *(bf16x4*)(xb + (size_t)t * I_DIM + lane * 4) = oa;
    *(bf16x4*)(xb + (size_t)t * I_DIM + 256 + lane * 4) = ob;

    float acc[8];
#pragma unroll
    for (int e = 0; e < 8; ++e) acc[e] = 0.f;
    float xv[8] = {va.x, va.y, va.z, va.w, vb.x, vb.y, vb.z, vb.w};
#pragma unroll
    for (int u = 0; u < 8; ++u) {
        int i = (u < 4) ? (lane * 4 + u) : (256 + lane * 4 + u - 4);
        const float4* wr = (const float4*)(Wg + (size_t)i * 8);
        float4 wa = wr[0], wb2 = wr[1];
        acc[0] = fmaf(xv[u], wa.x, acc[0]);
        acc[1] = fmaf(xv[u], wa.y, acc[1]);
        acc[2] = fmaf(xv[u], wa.z, acc[2]);
        acc[3] = fmaf(xv[u], wa.w, acc[3]);
        acc[4] = fmaf(xv[u], wb2.x, acc[4]);
        acc[5] = fmaf(xv[u], wb2.y, acc[5]);
        acc[6] = fmaf(xv[u], wb2.z, acc[6]);
        acc[7] = fmaf(xv[u], wb2.w, acc[7]);
    }
#pragma unroll
    for (int off = 32; off > 0; off >>= 1)
#pragma unroll
        for (int e = 0; e < 8; ++e)
            acc[e] += __shfl_xor(acc[e], off, 64);
    if (lane == 0) {
        float l[8];
#pragma unroll
        for (int e = 0; e < 8; ++e) l[e] = acc[e] + bg[e];
        int e0 = 0;
        for (int e = 1; e < 8; ++e) if (l[e] > l[e0]) e0 = e;
        int e1 = (e0 == 0) ? 1 : 0;
        for (int e = 0; e < 8; ++e) {
            if (e == e0) continue;
            if (l[e] > l[e1]) e1 = e;
        }
        float w0 = 1.f / (1.f + expf(l[e1] - l[e0]));  // p0/(p0+p1)
        tok_e[t * 2]     = e0;
        tok_e[t * 2 + 1] = e1;
        tok_w[t * 2]     = w0;
        tok_w[t * 2 + 1] = 1.f - w0;
    }
}

// ---------------------------------------------------------------------------
// Double-buffered LDS GEMM. 512 thr = 8 waves (wm=w>>1 in 0..3, wn=w&1).
// Block tile: 128m x 64n; K processed in 64-wide chunks, 1 barrier/chunk.
template <bool IS_FC1>
__global__ __launch_bounds__(512, 4) void moe_gemm(
    const __bf16* __restrict__ A, const float* __restrict__ Wf,
    const float* __restrict__ bias,
    int* __restrict__ counts, const int* __restrict__ tok_e,
    int* __restrict__ tok_slot,
    __bf16* __restrict__ hb, float* __restrict__ y2)
{
    constexpr int NW   = IS_FC1 ? H_DIM : O_DIM;   // W col count (row stride)
    constexpr int ASTR = IS_FC1 ? I_DIM : H_DIM;   // A row stride
    constexpr int NCH  = IS_FC1 ? 8 : 16;          // 64-k chunks

    const int bid  = blockIdx.x;
    const int e    = bid & 7;                      // XCD affinity
    const int rest = bid >> 3;
    const int nx   = IS_FC1 ? (rest & 31) : (rest & 7);
    const int my   = IS_FC1 ? (rest >> 5) : ((rest >> 3) & 1);
    const int kc   = IS_FC1 ? 0 : (rest >> 4);
    const int n0   = nx * 64;
    const int k0   = kc * 1024;
    const int off  = e * CAP;
    const float* W = Wf + (size_t)e * (IS_FC1 ? I_DIM * H_DIM : H_DIM * O_DIM);

    __shared__ __align__(16) __bf16 As[2][16 * 512];   // 16 x 1KB subtiles, 32 KB
    __shared__ __align__(16) __bf16 Bsh[2][64 * BSTRB];// [n][k] rows, 18 KB
    __shared__ int sl[IS_FC1 ? CAP : 1];
    __shared__ int sMe;

    const int tid = threadIdx.x;
    const int lane = tid & 63, w = tid >> 6;
    const int l15 = lane & 15, q = lane >> 4;
    const int wm = w >> 1, wn = w & 1;

    // ---- fc1: wave-0 ballot scan -> deterministic token-order slot list.
    if (IS_FC1 && w == 0) {
        int cnt = 0;
#pragma unroll
        for (int bb = 0; bb < 2; ++bb) {
            int vals[16];
#pragma unroll
            for (int c = 0; c < 16; ++c)
                vals[c] = tok_e[(bb * 16 + c) * 64 + lane];
#pragma unroll
            for (int c = 0; c < 16; ++c) {
                const int gidx = (bb * 16 + c) * 64 + lane;
                const bool hit = (vals[c] == e);
                const unsigned long long mk = __ballot(hit);
                if (hit) {
                    const int pos = cnt + __popcll(mk & ((1ull << lane) - 1));
                    sl[pos] = gidx >> 1;
                    if (nx == 0 && my == 0) tok_slot[gidx] = off + pos;
                }
                cnt += __popcll(mk);
            }
        }
        if (lane == 0) {
            sMe = cnt;
            if (nx == 0 && my == 0) counts[e] = cnt;
        }
    }
    __syncthreads();
    const int Me = IS_FC1 ? sMe : counts[e];
    if (Me == 0) return;

    // B staging unit: thread -> (k-pair p 0..31, n-quad c4 0..15).
    const int p = tid >> 4, c4 = tid & 15;
    const float* wB = W + (size_t)(k0 + 2 * p) * NW + n0 + c4 * 4;

    for (int mb = my * 128; mb < Me; mb += 256) {
        // lane's A gather row (serves its wave's 2 subtiles s=2w,2w+1):
        int rA = mb + w * 16 + l15; if (rA >= Me) rA = Me - 1;
        const __bf16* gA = IS_FC1 ? (A + (size_t)sl[rA] * ASTR)
                                  : (A + (size_t)(off + rA) * ASTR + k0);

        // ---- stage chunk 0 into buf 0
        gll16(gA + q * 8,      &As[0][(2 * w) * 512]);
        gll16(gA + 32 + q * 8, &As[0][(2 * w + 1) * 512]);
        {
            float4 r0 = *(const float4*)wB;
            float4 r1 = *(const float4*)(wB + NW);
            const float* f0 = (const float*)&r0;
            const float* f1 = (const float*)&r1;
#pragma unroll
            for (int j = 0; j < 4; ++j) {
                bf16x2 pk;
                pk[0] = (__bf16)f0[j];
                pk[1] = (__bf16)f1[j];
                *(bf16x2*)&Bsh[0][(c4 * 4 + j) * BSTRB + 2 * p] = pk;
            }
        }
        __syncthreads();                 // chunk 0 resident

        f32x4 acc[2][2] = {};
        for (int c = 0; c < NCH; ++c) {
            const int cb = c & 1, nb = cb ^ 1;
            const bool more = (c + 1 < NCH);
            float4 r0, r1;
            if (more) {                  // issue next-chunk loads EARLY
                const float* wp = wB + (size_t)(c + 1) * 64 * NW;
                r0 = *(const float4*)wp;
                r1 = *(const float4*)(wp + NW);
                gll16(gA + (c + 1) * 64 + q * 8,      &As[nb][(2 * w) * 512]);
                gll16(gA + (c + 1) * 64 + 32 + q * 8, &As[nb][(2 * w + 1) * 512]);
            }
            // ---- compute chunk c from LDS only
#pragma unroll
            for (int sk = 0; sk < 2; ++sk) {
                bf16x8 a0 = *(const bf16x8*)
                    &As[cb][((wm * 2 + 0) * 2 + sk) * 512 + lane * 8];
                bf16x8 a1 = *(const bf16x8*)
                    &As[cb][((wm * 2 + 1) * 2 + sk) * 512 + lane * 8];
                bf16x8 b0 = *(const bf16x8*)
                    &Bsh[cb][((wn * 2 + 0) * 16 + l15) * BSTRB + sk * 32 + q * 8];
                bf16x8 b1 = *(const bf16x8*)
                    &Bsh[cb][((wn * 2 + 1) * 16 + l15) * BSTRB + sk * 32 + q * 8];
                acc[0][0] = MFMA16(a0, b0, acc[0][0], 0, 0, 0);
                acc[0][1] = MFMA16(a0, b1, acc[0][1], 0, 0, 0);
                acc[1][0] = MFMA16(a1, b0, acc[1][0], 0, 0, 0);
                acc[1][1] = MFMA16(a1, b1, acc[1][1], 0, 0, 0);
            }
            if (more) {                  // write-LATE B cvt (T14 split)
                const float* f0 = (const float*)&r0;
                const float* f1 = (const float*)&r1;
#pragma unroll
                for (int j = 0; j < 4; ++j) {
                    bf16x2 pk;
                    pk[0] = (__bf16)f0[j];
                    pk[1] = (__bf16)f1[j];
                    *(bf16x2*)&Bsh[nb][(c4 * 4 + j) * BSTRB + 2 * p] = pk;
                }
            }
            __syncthreads();             // next chunk resident; prev readers done
        }

        // ---- epilogue: C/D layout col=l15, row=q*4+r (verified m89)
#pragma unroll
        for (int j = 0; j < 2; ++j) {
            const int gn = n0 + (wn * 2 + j) * 16 + l15;
            if (IS_FC1) {
                const float bv = bias[e * H_DIM + gn];
#pragma unroll
                for (int i = 0; i < 2; ++i)
#pragma unroll
                    for (int rr = 0; rr < 4; ++rr) {
                        int m = mb + (wm * 2 + i) * 16 + q * 4 + rr;
                        if (m < Me) {
                            float v = acc[i][j][rr] + bv;
                            hb[(size_t)(off + m) * H_DIM + gn] =
                                (__bf16)fmaxf(v, 0.f);
                        }
                    }
            } else {
#pragma unroll
                for (int i = 0; i < 2; ++i)
#pragma unroll
                    for (int rr = 0; rr < 4; ++rr) {
                        int m = mb + (wm * 2 + i) * 16 + q * 4 + rr;
                        if (m < Me)
                            y2[((size_t)kc * (E_NUM * CAP) + off + m) * O_DIM + gn] =
                                acc[i][j][rr];
                    }
            }
        }
    }
}

// ---------------------------------------------------------------------------
// out[t][c] = sum_k w_k * (b2[e_k][c] + sum_kc y2[kc][slot_k][c])
__global__ __launch_bounds__(256) void combine_kernel(
    const float* __restrict__ y2, const float* __restrict__ b2,
    const int* __restrict__ tok_slot, const int* __restrict__ tok_e,
    const float* __restrict__ tok_w, float* __restrict__ out)
{
    const int idx = blockIdx.x * 256 + threadIdx.x;   // B*O/4
    const int t = idx >> 7;
    const int c = (idx & 127) * 4;
    float4 sum = {0.f, 0.f, 0.f, 0.f};
#pragma unroll
    for (int k = 0; k < 2; ++k) {
        const int s = tok_slot[t * 2 + k];
        const int e = tok_e[t * 2 + k];
        const float wgt = tok_w[t * 2 + k];
        float4 a = *(const float4*)(b2 + (size_t)e * O_DIM + c);
#pragma unroll
        for (int kc = 0; kc < 2; ++kc) {
            float4 v = *(const float4*)
                (y2 + ((size_t)kc * (E_NUM * CAP) + s) * O_DIM + c);
            a.x += v.x; a.y += v.y; a.z += v.z; a.w += v.w;
        }
        sum.x += wgt * a.x; sum.y += wgt * a.y;
        sum.z += wgt * a.z; sum.w += wgt * a.w;
    }
    *(float4*)(out + (size_t)t * O_DIM + c) = sum;
}

// ===========================================================================
extern "C" void kernel_launch(void* const* d_in, const int* in_sizes, int n_in,
                              void* d_out, int out_size, void* d_ws, size_t ws_size,
                              hipStream_t stream)
{
    const float* x  = (const float*)d_in[0];
    const float* Wg = (const float*)d_in[1];
    const float* bg = (const float*)d_in[2];
    const float* W1 = (const float*)d_in[3];
    const float* b1 = (const float*)d_in[4];
    const float* W2 = (const float*)d_in[5];
    const float* b2 = (const float*)d_in[6];
    float* out = (float*)d_out;
    char* ws = (char*)d_ws;

    int*    counts   = (int*)(ws + WS_COUNTS);
    int*    tok_e    = (int*)(ws + WS_TOK_E);
    float*  tok_w    = (float*)(ws + WS_TOK_W);
    int*    tok_slot = (int*)(ws + WS_TOK_SLOT);
    __bf16* xb       = (__bf16*)(ws + WS_XB);
    __bf16* hb       = (__bf16*)(ws + WS_HB);
    float*  y2       = (float*)(ws + WS_Y2);

    gating_kernel<<<B_TOK / 4, 256, 0, stream>>>(x, Wg, bg, xb, tok_e, tok_w);
    // fc1: 8e x 32nx x 2my = 512 blocks (2/CU), e = bid&7
    moe_gemm<true><<<512, 512, 0, stream>>>(
        xb, W1, b1, counts, tok_e, tok_slot, hb, y2);
    // fc2: 8e x 8nx x 2my x 2kc = 256 blocks
    moe_gemm<false><<<256, 512, 0, stream>>>(
        hb, W2, b2, counts, tok_e, tok_slot, hb, y2);
    combine_kernel<<<(B_TOK * O_DIM / 4) / 256, 256, 0, stream>>>(
        y2, b2, tok_slot, tok_e, tok_w, out);
}